// Round 1
// baseline (440.302 us; speedup 1.0000x reference)
//
#include <hip/hip_runtime.h>
#include <stdint.h>

#define BB 4
#define SS 1024
#define DD 1024
#define HH 16

typedef __attribute__((ext_vector_type(8))) __bf16 bf16x8;
typedef __attribute__((ext_vector_type(4))) float f32x4;

__device__ __forceinline__ unsigned short f2bf(float f) {
  union { float ff; uint32_t u; } a; a.ff = f;
  uint32_t r = a.u + 0x7fffu + ((a.u >> 16) & 1u);
  return (unsigned short)(r >> 16);
}

__device__ __forceinline__ f32x4 mfma16(bf16x8 a, bf16x8 b, f32x4 c) {
  return __builtin_amdgcn_mfma_f32_16x16x32_bf16(a, b, c, 0, 0, 0);
}

// global -> LDS direct copy, 16B per lane; LDS dest is wave-uniform base + lane*16
__device__ __forceinline__ void async16(const unsigned short* g, unsigned short* l) {
  __builtin_amdgcn_global_load_lds(
      (__attribute__((address_space(1))) void*)(g),
      (__attribute__((address_space(3))) void*)(l), 16u, 0, 0u);
}

// ---------- W (K x N fp32) -> Wt (N x K bf16) ----------
__global__ __launch_bounds__(256) void wtrans_kernel(const float* __restrict__ W,
                                                     unsigned short* __restrict__ Wt) {
  __shared__ unsigned short t[64][65];
  const int k0 = blockIdx.x * 64, n0 = blockIdx.y * 64;
  const int c = threadIdx.x & 63, r0 = threadIdx.x >> 6;
#pragma unroll
  for (int i = 0; i < 16; ++i) {
    int r = i * 4 + r0;
    t[r][c] = f2bf(W[(size_t)(k0 + r) * DD + n0 + c]);
  }
  __syncthreads();
#pragma unroll
  for (int i = 0; i < 16; ++i) {
    int n = i * 4 + r0;
    Wt[(size_t)(n0 + n) * DD + k0 + c] = t[c][n];
  }
}

// ---------- LayerNorm (fp32 math) -> bf16 ----------
__global__ __launch_bounds__(256) void ln_kernel(const float* __restrict__ X,
                                                 const float* __restrict__ gamma,
                                                 const float* __restrict__ beta,
                                                 unsigned short* __restrict__ Xn) {
  const int row = blockIdx.x;
  const int tid = threadIdx.x;
  const float* xr = X + (size_t)row * DD;
  float4 v = ((const float4*)xr)[tid];
  float s = v.x + v.y + v.z + v.w;
  float s2 = v.x * v.x + v.y * v.y + v.z * v.z + v.w * v.w;
#pragma unroll
  for (int off = 1; off < 64; off <<= 1) {
    s += __shfl_xor(s, off);
    s2 += __shfl_xor(s2, off);
  }
  __shared__ float red[8];
  const int wv = tid >> 6, lane = tid & 63;
  if (lane == 0) { red[wv] = s; red[4 + wv] = s2; }
  __syncthreads();
  s = red[0] + red[1] + red[2] + red[3];
  s2 = red[4] + red[5] + red[6] + red[7];
  const float mu = s * (1.0f / DD);
  const float rs = rsqrtf(s2 * (1.0f / DD) - mu * mu + 1e-5f);
  float4 g = ((const float4*)gamma)[tid];
  float4 bt = ((const float4*)beta)[tid];
  ushort4 o;
  o.x = f2bf((v.x - mu) * rs * g.x + bt.x);
  o.y = f2bf((v.y - mu) * rs * g.y + bt.y);
  o.z = f2bf((v.z - mu) * rs * g.z + bt.z);
  o.w = f2bf((v.w - mu) * rs * g.w + bt.w);
  ((ushort4*)(Xn + (size_t)row * DD))[tid] = o;
}

// ---------- QKV GEMM: C = Xn (M x K) * Wt^T (Wt is N x K), m97-style 128x128 tile ----------
// z==0 -> Qb (M x N bf16), z==1 -> Kb (M x N bf16), z==2 -> Vt transposed (B*H*64, S) bf16
__global__ __launch_bounds__(256) void gemm_qkv_kernel(
    const unsigned short* __restrict__ Xn,
    const unsigned short* __restrict__ Wtq, const unsigned short* __restrict__ Wtk,
    const unsigned short* __restrict__ Wtv,
    const float* __restrict__ bq, const float* __restrict__ bk, const float* __restrict__ bv,
    unsigned short* __restrict__ Qb, unsigned short* __restrict__ Kb,
    unsigned short* __restrict__ Vt) {
  __shared__ unsigned short sA[128 * 32];
  __shared__ unsigned short sB[128 * 32];
  const int z = blockIdx.z;
  const unsigned short* Wt = (z == 0) ? Wtq : (z == 1) ? Wtk : Wtv;
  const float* bias = (z == 0) ? bq : (z == 1) ? bk : bv;
  const int tid = threadIdx.x;
  const int lane = tid & 63, wv = tid >> 6;
  const int quad = lane >> 4, l16 = lane & 15;
  const int m0 = blockIdx.x * 128, n0 = blockIdx.y * 128;
  const int wm = (wv & 1) * 64, wn = (wv >> 1) * 64;

  f32x4 acc[4][4];
#pragma unroll
  for (int i = 0; i < 4; ++i)
#pragma unroll
    for (int j = 0; j < 4; ++j) acc[i][j] = (f32x4){0.f, 0.f, 0.f, 0.f};

  for (int kt = 0; kt < DD; kt += 32) {
    __syncthreads();
#pragma unroll
    for (int it = 0; it < 2; ++it) {
      const int c = it * 256 + tid;
      const int row = c >> 2, kc = c & 3;
      async16(Xn + (size_t)(m0 + row) * DD + kt + kc * 8, &sA[(it * 256 + wv * 64) * 8]);
      async16(Wt + (size_t)(n0 + row) * DD + kt + kc * 8, &sB[(it * 256 + wv * 64) * 8]);
    }
    __syncthreads();
    bf16x8 af[4], bfr[4];
#pragma unroll
    for (int i = 0; i < 4; ++i) af[i] = *(const bf16x8*)&sA[(wm + i * 16 + l16) * 32 + quad * 8];
#pragma unroll
    for (int j = 0; j < 4; ++j) bfr[j] = *(const bf16x8*)&sB[(wn + j * 16 + l16) * 32 + quad * 8];
#pragma unroll
    for (int i = 0; i < 4; ++i)
#pragma unroll
      for (int j = 0; j < 4; ++j) acc[i][j] = mfma16(af[i], bfr[j], acc[i][j]);
  }

#pragma unroll
  for (int i = 0; i < 4; ++i) {
    const int gm0 = m0 + wm + i * 16 + quad * 4;  // 4 consecutive rows (same b)
#pragma unroll
    for (int j = 0; j < 4; ++j) {
      const int gn = n0 + wn + j * 16 + l16;
      const float bb = bias[gn];
      if (z < 2) {
        unsigned short* Out = (z == 0) ? Qb : Kb;
#pragma unroll
        for (int r = 0; r < 4; ++r)
          Out[(size_t)(gm0 + r) * DD + gn] = f2bf(acc[i][j][r] + bb);
      } else {
        const int b = gm0 >> 10, s0 = gm0 & 1023;
        const int h = gn >> 6, dv = gn & 63;
        ushort4 pk;
        pk.x = f2bf(acc[i][j][0] + bb);
        pk.y = f2bf(acc[i][j][1] + bb);
        pk.z = f2bf(acc[i][j][2] + bb);
        pk.w = f2bf(acc[i][j][3] + bb);
        *(ushort4*)&Vt[((size_t)((b * HH + h) * 64 + dv)) * SS + s0] = pk;
      }
    }
  }
}

// ---------- fused attention: per (b,h,q-tile 128) ----------
// pass1: denominators (no max-sub; scores are small by construction)
// pass2: recompute scores, write normalized attn, P->LDS, PV MFMA
__global__ __launch_bounds__(256) void attn_kernel(
    const unsigned short* __restrict__ Qb, const unsigned short* __restrict__ Kb,
    const unsigned short* __restrict__ Vt, const float* __restrict__ X,
    const int* __restrict__ lens, float* __restrict__ seq_out,
    float* __restrict__ attn_out) {
  __shared__ unsigned short sQV[128 * 64];   // Q tile in pass1, V^T tile (64x128) in pass2
  __shared__ unsigned short sK[128 * 64];
  __shared__ unsigned short sP[4 * 32 * 128]; // per-wave P scratch (32x128 bf16)

  const int tid = threadIdx.x;
  const int lane = tid & 63, wv = tid >> 6;
  const int quad = lane >> 4, l16 = lane & 15;
  const int qt = blockIdx.x, h = blockIdx.y, b = blockIdx.z;
  const int q0 = qt * 128;
  const int len = lens[b];
  const int KE = min(q0 + 128, len);
  const int NKT = (KE + 127) >> 7;           // k-tiles with any valid entry
  const float SCL = 0.1803368801111204f;     // (1/sqrt(64)) * log2(e) / ... = 0.125*log2e

#pragma unroll
  for (int it = 0; it < 4; ++it) {
    const int c = it * 256 + tid;
    async16(Qb + (size_t)(b * SS + q0 + (c >> 3)) * DD + h * 64 + (c & 7) * 8,
            &sQV[(it * 256 + wv * 64) * 8]);
  }
  __syncthreads();

  bf16x8 qf[2][2];
#pragma unroll
  for (int i = 0; i < 2; ++i)
#pragma unroll
    for (int dd = 0; dd < 2; ++dd)
      qf[i][dd] = *(const bf16x8*)&sQV[(wv * 32 + i * 16 + l16) * 64 + dd * 32 + quad * 8];

  float lsum[2][4];
#pragma unroll
  for (int i = 0; i < 2; ++i)
#pragma unroll
    for (int r = 0; r < 4; ++r) lsum[i][r] = 0.f;

  // ---- pass 1 ----
  for (int kt = 0; kt < NKT; ++kt) {
    const int k0 = kt * 128;
    __syncthreads();
#pragma unroll
    for (int it = 0; it < 4; ++it) {
      const int c = it * 256 + tid;
      async16(Kb + (size_t)(b * SS + k0 + (c >> 3)) * DD + h * 64 + (c & 7) * 8,
              &sK[(it * 256 + wv * 64) * 8]);
    }
    __syncthreads();
    const bool edge = (kt == qt) || (k0 + 128 > len);
#pragma unroll
    for (int j = 0; j < 8; ++j) {
      const bf16x8 kf0 = *(const bf16x8*)&sK[(j * 16 + l16) * 64 + quad * 8];
      const bf16x8 kf1 = *(const bf16x8*)&sK[(j * 16 + l16) * 64 + 32 + quad * 8];
      const int k = k0 + j * 16 + l16;
#pragma unroll
      for (int i = 0; i < 2; ++i) {
        f32x4 sc = (f32x4){0.f, 0.f, 0.f, 0.f};
        sc = mfma16(qf[i][0], kf0, sc);
        sc = mfma16(qf[i][1], kf1, sc);
        const int qq = q0 + wv * 32 + i * 16 + quad * 4;
#pragma unroll
        for (int r = 0; r < 4; ++r) {
          float sv = sc[r] * SCL;
          if (edge && ((k > qq + r) || (k >= len))) sv = -1e30f;
          lsum[i][r] += __builtin_amdgcn_exp2f(sv);
        }
      }
    }
  }

  float linv[2][4];
#pragma unroll
  for (int i = 0; i < 2; ++i)
#pragma unroll
    for (int r = 0; r < 4; ++r) {
      float l = lsum[i][r];
      l += __shfl_xor(l, 1);
      l += __shfl_xor(l, 2);
      l += __shfl_xor(l, 4);
      l += __shfl_xor(l, 8);
      linv[i][r] = 1.0f / l;
    }

  // ---- pass 2 ----
  f32x4 oacc[2][4];
#pragma unroll
  for (int i = 0; i < 2; ++i)
#pragma unroll
    for (int jv = 0; jv < 4; ++jv) oacc[i][jv] = (f32x4){0.f, 0.f, 0.f, 0.f};

  const size_t abase = (size_t)(b * HH + h) * SS * SS;

  for (int kt = 0; kt < NKT; ++kt) {
    const int k0 = kt * 128;
    __syncthreads();
#pragma unroll
    for (int it = 0; it < 4; ++it) {
      const int c = it * 256 + tid;
      async16(Kb + (size_t)(b * SS + k0 + (c >> 3)) * DD + h * 64 + (c & 7) * 8,
              &sK[(it * 256 + wv * 64) * 8]);
      async16(Vt + ((size_t)((b * HH + h) * 64 + (c >> 4))) * SS + k0 + (c & 15) * 8,
              &sQV[(it * 256 + wv * 64) * 8]);
    }
    __syncthreads();
    const bool edge = (kt == qt) || (k0 + 128 > len);
#pragma unroll
    for (int j = 0; j < 8; ++j) {
      const bf16x8 kf0 = *(const bf16x8*)&sK[(j * 16 + l16) * 64 + quad * 8];
      const bf16x8 kf1 = *(const bf16x8*)&sK[(j * 16 + l16) * 64 + 32 + quad * 8];
      const int k = k0 + j * 16 + l16;
#pragma unroll
      for (int i = 0; i < 2; ++i) {
        f32x4 sc = (f32x4){0.f, 0.f, 0.f, 0.f};
        sc = mfma16(qf[i][0], kf0, sc);
        sc = mfma16(qf[i][1], kf1, sc);
        const int qq = q0 + wv * 32 + i * 16 + quad * 4;
        const int prow = wv * 4096 + (i * 16 + quad * 4) * 128 + j * 16 + l16;
#pragma unroll
        for (int r = 0; r < 4; ++r) {
          float sv = sc[r] * SCL;
          if (edge && ((k > qq + r) || (k >= len))) sv = -1e30f;
          const float p = __builtin_amdgcn_exp2f(sv) * linv[i][r];
          attn_out[abase + (size_t)(qq + r) * SS + k] = p;
          sP[prow + r * 128] = f2bf(p);
        }
      }
    }
    // PV: O += P (32x128) * V (128x64), per wave
#pragma unroll
    for (int kk = 0; kk < 4; ++kk) {
      bf16x8 vf[4];
#pragma unroll
      for (int jv = 0; jv < 4; ++jv)
        vf[jv] = *(const bf16x8*)&sQV[(jv * 16 + l16) * 128 + kk * 32 + quad * 8];
#pragma unroll
      for (int i = 0; i < 2; ++i) {
        const bf16x8 pf =
            *(const bf16x8*)&sP[wv * 4096 + (i * 16 + l16) * 128 + kk * 32 + quad * 8];
#pragma unroll
        for (int jv = 0; jv < 4; ++jv) oacc[i][jv] = mfma16(pf, vf[jv], oacc[i][jv]);
      }
    }
  }

  // zero-fill fully-masked column range [NKT*128, S)
  const int Z = SS - NKT * 128;
  if (Z > 0) {
    const int rr0 = tid >> 3;
    const int cf = (tid & 7) * 4;
    for (int rr = rr0; rr < 128; rr += 32) {
      float* dst = attn_out + abase + (size_t)(q0 + rr) * SS + NKT * 128 + cf;
      for (int c8 = 0; c8 < (Z >> 5); ++c8)
        *(float4*)(dst + c8 * 32) = make_float4(0.f, 0.f, 0.f, 0.f);
    }
  }

  // epilogue: seq = x + O (heads write disjoint 64-col slices)
#pragma unroll
  for (int i = 0; i < 2; ++i) {
    const int qg = q0 + wv * 32 + i * 16 + quad * 4;
#pragma unroll
    for (int jv = 0; jv < 4; ++jv) {
      const int col = h * 64 + jv * 16 + l16;
#pragma unroll
      for (int r = 0; r < 4; ++r) {
        const size_t idx = (size_t)(b * SS + qg + r) * DD + col;
        seq_out[idx] = X[idx] + oacc[i][jv][r];
      }
    }
  }
}

extern "C" void kernel_launch(void* const* d_in, const int* in_sizes, int n_in,
                              void* d_out, int out_size, void* d_ws, size_t ws_size,
                              hipStream_t stream) {
  (void)in_sizes; (void)n_in; (void)out_size; (void)ws_size;
  const float* X     = (const float*)d_in[0];
  const int*   lens  = (const int*)d_in[3];
  const float* gamma = (const float*)d_in[4];
  const float* beta  = (const float*)d_in[5];
  const float* Wq    = (const float*)d_in[6];
  const float* bq    = (const float*)d_in[7];
  const float* Wk    = (const float*)d_in[8];
  const float* bk    = (const float*)d_in[9];
  const float* Wv    = (const float*)d_in[10];
  const float* bv    = (const float*)d_in[11];

  // workspace layout (38 MB total)
  char* ws = (char*)d_ws;
  unsigned short* Xn  = (unsigned short*)(ws);                      // 8 MB  (4096x1024 bf16)
  unsigned short* Qb  = (unsigned short*)(ws + ((size_t)8  << 20)); // 8 MB
  unsigned short* Kb  = (unsigned short*)(ws + ((size_t)16 << 20)); // 8 MB
  unsigned short* Vt  = (unsigned short*)(ws + ((size_t)24 << 20)); // 8 MB  (B*H*64, S) bf16
  unsigned short* Wtq = (unsigned short*)(ws + ((size_t)32 << 20)); // 2 MB
  unsigned short* Wtk = (unsigned short*)(ws + ((size_t)34 << 20)); // 2 MB
  unsigned short* Wtv = (unsigned short*)(ws + ((size_t)36 << 20)); // 2 MB

  float* seq_out  = (float*)d_out;                         // (B,S,1024)
  float* attn_out = seq_out + (size_t)BB * SS * DD;        // (B,H,S,S)

  wtrans_kernel<<<dim3(16, 16), 256, 0, stream>>>(Wq, Wtq);
  wtrans_kernel<<<dim3(16, 16), 256, 0, stream>>>(Wk, Wtk);
  wtrans_kernel<<<dim3(16, 16), 256, 0, stream>>>(Wv, Wtv);
  ln_kernel<<<dim3(BB * SS), 256, 0, stream>>>(X, gamma, beta, Xn);
  gemm_qkv_kernel<<<dim3(32, 8, 3), 256, 0, stream>>>(Xn, Wtq, Wtk, Wtv, bq, bk, bv, Qb, Kb, Vt);
  attn_kernel<<<dim3(8, HH, BB), 256, 0, stream>>>(Qb, Kb, Vt, X, lens, seq_out, attn_out);
}

// Round 2
// 436.580 us; speedup vs baseline: 1.0085x; 1.0085x over previous
//
#include <hip/hip_runtime.h>
#include <stdint.h>

#define BB 4
#define SS 1024
#define DD 1024
#define HH 16

typedef __attribute__((ext_vector_type(8))) __bf16 bf16x8;
typedef __attribute__((ext_vector_type(4))) float f32x4;

__device__ __forceinline__ unsigned short f2bf(float f) {
  union { float ff; uint32_t u; } a; a.ff = f;
  uint32_t r = a.u + 0x7fffu + ((a.u >> 16) & 1u);
  return (unsigned short)(r >> 16);
}

__device__ __forceinline__ float bf2f(unsigned short u) {
  union { uint32_t uu; float ff; } a; a.uu = ((uint32_t)u) << 16;
  return a.ff;
}

__device__ __forceinline__ f32x4 mfma16(bf16x8 a, bf16x8 b, f32x4 c) {
  return __builtin_amdgcn_mfma_f32_16x16x32_bf16(a, b, c, 0, 0, 0);
}

// global -> LDS direct copy, 16B per lane; LDS dest is wave-uniform base + lane*16
__device__ __forceinline__ void async16(const unsigned short* g, unsigned short* l) {
  __builtin_amdgcn_global_load_lds(
      (__attribute__((address_space(1))) void*)(g),
      (__attribute__((address_space(3))) void*)(l), 16u, 0, 0u);
}

// ---------- W (K x N fp32) -> Wt (N x K bf16), z selects which of Q/K/V ----------
__global__ __launch_bounds__(256) void wtrans_kernel(const float* __restrict__ Wq,
                                                     const float* __restrict__ Wk,
                                                     const float* __restrict__ Wv,
                                                     unsigned short* __restrict__ Wtq,
                                                     unsigned short* __restrict__ Wtk,
                                                     unsigned short* __restrict__ Wtv) {
  __shared__ unsigned short t[64][65];
  const int z = blockIdx.z;
  const float* W = (z == 0) ? Wq : (z == 1) ? Wk : Wv;
  unsigned short* Wt = (z == 0) ? Wtq : (z == 1) ? Wtk : Wtv;
  const int k0 = blockIdx.x * 64, n0 = blockIdx.y * 64;
  const int c = threadIdx.x & 63, r0 = threadIdx.x >> 6;
#pragma unroll
  for (int i = 0; i < 16; ++i) {
    int r = i * 4 + r0;
    t[r][c] = f2bf(W[(size_t)(k0 + r) * DD + n0 + c]);
  }
  __syncthreads();
#pragma unroll
  for (int i = 0; i < 16; ++i) {
    int n = i * 4 + r0;
    Wt[(size_t)(n0 + n) * DD + k0 + c] = t[c][n];
  }
}

// ---------- LayerNorm (fp32 math) -> bf16 ----------
__global__ __launch_bounds__(256) void ln_kernel(const float* __restrict__ X,
                                                 const float* __restrict__ gamma,
                                                 const float* __restrict__ beta,
                                                 unsigned short* __restrict__ Xn) {
  const int row = blockIdx.x;
  const int tid = threadIdx.x;
  const float* xr = X + (size_t)row * DD;
  float4 v = ((const float4*)xr)[tid];
  float s = v.x + v.y + v.z + v.w;
  float s2 = v.x * v.x + v.y * v.y + v.z * v.z + v.w * v.w;
#pragma unroll
  for (int off = 1; off < 64; off <<= 1) {
    s += __shfl_xor(s, off);
    s2 += __shfl_xor(s2, off);
  }
  __shared__ float red[8];
  const int wv = tid >> 6, lane = tid & 63;
  if (lane == 0) { red[wv] = s; red[4 + wv] = s2; }
  __syncthreads();
  s = red[0] + red[1] + red[2] + red[3];
  s2 = red[4] + red[5] + red[6] + red[7];
  const float mu = s * (1.0f / DD);
  const float rs = rsqrtf(s2 * (1.0f / DD) - mu * mu + 1e-5f);
  float4 g = ((const float4*)gamma)[tid];
  float4 bt = ((const float4*)beta)[tid];
  ushort4 o;
  o.x = f2bf((v.x - mu) * rs * g.x + bt.x);
  o.y = f2bf((v.y - mu) * rs * g.y + bt.y);
  o.z = f2bf((v.z - mu) * rs * g.z + bt.z);
  o.w = f2bf((v.w - mu) * rs * g.w + bt.w);
  ((ushort4*)(Xn + (size_t)row * DD))[tid] = o;
}

// ---------- QKV GEMM: C = Xn (M x K) * Wt^T (Wt is N x K), 128x128 tile ----------
// z==0 -> Qb, z==1 -> Kb (M x N bf16, LDS-staged vectorized store)
// z==2 -> Vt transposed (B*H*64, S) bf16 (direct ushort4, contiguous along s)
__global__ __launch_bounds__(256) void gemm_qkv_kernel(
    const unsigned short* __restrict__ Xn,
    const unsigned short* __restrict__ Wtq, const unsigned short* __restrict__ Wtk,
    const unsigned short* __restrict__ Wtv,
    const float* __restrict__ bq, const float* __restrict__ bk, const float* __restrict__ bv,
    unsigned short* __restrict__ Qb, unsigned short* __restrict__ Kb,
    unsigned short* __restrict__ Vt) {
  // union: [sA 128x32 | sB 128x32] during K-loop, sC 128x136 in epilogue
  __shared__ __align__(16) unsigned short smem[128 * 136];
  unsigned short* sA = smem;
  unsigned short* sB = smem + 128 * 32;
  const int z = blockIdx.z;
  const unsigned short* Wt = (z == 0) ? Wtq : (z == 1) ? Wtk : Wtv;
  const float* bias = (z == 0) ? bq : (z == 1) ? bk : bv;
  const int tid = threadIdx.x;
  const int lane = tid & 63, wv = tid >> 6;
  const int quad = lane >> 4, l16 = lane & 15;
  const int m0 = blockIdx.x * 128, n0 = blockIdx.y * 128;
  const int wm = (wv & 1) * 64, wn = (wv >> 1) * 64;

  f32x4 acc[4][4];
#pragma unroll
  for (int i = 0; i < 4; ++i)
#pragma unroll
    for (int j = 0; j < 4; ++j) acc[i][j] = (f32x4){0.f, 0.f, 0.f, 0.f};

  for (int kt = 0; kt < DD; kt += 32) {
    __syncthreads();
#pragma unroll
    for (int it = 0; it < 2; ++it) {
      const int c = it * 256 + tid;
      const int row = c >> 2, kc = c & 3;
      async16(Xn + (size_t)(m0 + row) * DD + kt + kc * 8, &sA[(it * 256 + wv * 64) * 8]);
      async16(Wt + (size_t)(n0 + row) * DD + kt + kc * 8, &sB[(it * 256 + wv * 64) * 8]);
    }
    __syncthreads();
    bf16x8 af[4], bfr[4];
#pragma unroll
    for (int i = 0; i < 4; ++i) af[i] = *(const bf16x8*)&sA[(wm + i * 16 + l16) * 32 + quad * 8];
#pragma unroll
    for (int j = 0; j < 4; ++j) bfr[j] = *(const bf16x8*)&sB[(wn + j * 16 + l16) * 32 + quad * 8];
#pragma unroll
    for (int i = 0; i < 4; ++i)
#pragma unroll
      for (int j = 0; j < 4; ++j) acc[i][j] = mfma16(af[i], bfr[j], acc[i][j]);
  }

  if (z < 2) {
    // stage C tile (bf16) in padded LDS, then vectorized 16B stores
    __syncthreads();
    unsigned short* sC = smem;  // 128 x 136
#pragma unroll
    for (int i = 0; i < 4; ++i) {
      const int lr0 = wm + i * 16 + quad * 4;
#pragma unroll
      for (int j = 0; j < 4; ++j) {
        const int lc = wn + j * 16 + l16;
        const float bb = bias[n0 + lc];
#pragma unroll
        for (int r = 0; r < 4; ++r) sC[(lr0 + r) * 136 + lc] = f2bf(acc[i][j][r] + bb);
      }
    }
    __syncthreads();
    unsigned short* Out = (z == 0) ? Qb : Kb;
    const int rr = tid >> 4, c8 = (tid & 15) * 8;
#pragma unroll
    for (int it = 0; it < 8; ++it) {
      const int row = it * 16 + rr;
      *(uint4*)&Out[(size_t)(m0 + row) * DD + n0 + c8] = *(const uint4*)&sC[row * 136 + c8];
    }
  } else {
#pragma unroll
    for (int i = 0; i < 4; ++i) {
      const int gm0 = m0 + wm + i * 16 + quad * 4;
#pragma unroll
      for (int j = 0; j < 4; ++j) {
        const int gn = n0 + wn + j * 16 + l16;
        const float bb = bias[gn];
        const int b = gm0 >> 10, s0 = gm0 & 1023;
        const int h = gn >> 6, dv = gn & 63;
        ushort4 pk;
        pk.x = f2bf(acc[i][j][0] + bb);
        pk.y = f2bf(acc[i][j][1] + bb);
        pk.z = f2bf(acc[i][j][2] + bb);
        pk.w = f2bf(acc[i][j][3] + bb);
        *(ushort4*)&Vt[((size_t)((b * HH + h) * 64 + dv)) * SS + s0] = pk;
      }
    }
  }
}

// ---------- fused attention: per (b,h,q-tile 128) ----------
// pass1: denominators (no max-sub; scores are small by construction)
// pass2: recompute scores, stage P in LDS, vectorized attn write, PV MFMA
__global__ __launch_bounds__(256) void attn_kernel(
    const unsigned short* __restrict__ Qb, const unsigned short* __restrict__ Kb,
    const unsigned short* __restrict__ Vt, const float* __restrict__ X,
    const int* __restrict__ lens, float* __restrict__ seq_out,
    float* __restrict__ attn_out) {
  __shared__ unsigned short sQV[128 * 64];    // Q tile in pass1, V^T tile (64x128) in pass2
  __shared__ unsigned short sK[128 * 64];
  __shared__ unsigned short sP[4 * 32 * 128]; // per-wave P scratch (32x128 bf16)

  const int tid = threadIdx.x;
  const int lane = tid & 63, wv = tid >> 6;
  const int quad = lane >> 4, l16 = lane & 15;
  const int h = blockIdx.y, b = blockIdx.z;
  // balance: co-resident block pairs (same x,y; z +/-2) get complementary depth
  const int qt = (b & 2) ? (7 - (int)blockIdx.x) : (int)blockIdx.x;
  const int q0 = qt * 128;
  const int len = lens[b];
  const int KE = min(q0 + 128, len);
  const int NKT = (KE + 127) >> 7;           // k-tiles with any valid entry
  const float SCL = 0.1803368801111204f;     // 0.125 * log2(e)

#pragma unroll
  for (int it = 0; it < 4; ++it) {
    const int c = it * 256 + tid;
    async16(Qb + (size_t)(b * SS + q0 + (c >> 3)) * DD + h * 64 + (c & 7) * 8,
            &sQV[(it * 256 + wv * 64) * 8]);
  }
  __syncthreads();

  bf16x8 qf[2][2];
#pragma unroll
  for (int i = 0; i < 2; ++i)
#pragma unroll
    for (int dd = 0; dd < 2; ++dd)
      qf[i][dd] = *(const bf16x8*)&sQV[(wv * 32 + i * 16 + l16) * 64 + dd * 32 + quad * 8];

  float lsum[2][4];
#pragma unroll
  for (int i = 0; i < 2; ++i)
#pragma unroll
    for (int r = 0; r < 4; ++r) lsum[i][r] = 0.f;

  // ---- pass 1: denominators ----
  for (int kt = 0; kt < NKT; ++kt) {
    const int k0 = kt * 128;
    __syncthreads();
#pragma unroll
    for (int it = 0; it < 4; ++it) {
      const int c = it * 256 + tid;
      async16(Kb + (size_t)(b * SS + k0 + (c >> 3)) * DD + h * 64 + (c & 7) * 8,
              &sK[(it * 256 + wv * 64) * 8]);
    }
    __syncthreads();
    const bool edge = (kt == qt) || (k0 + 128 > len);
#pragma unroll
    for (int j = 0; j < 8; ++j) {
      const bf16x8 kf0 = *(const bf16x8*)&sK[(j * 16 + l16) * 64 + quad * 8];
      const bf16x8 kf1 = *(const bf16x8*)&sK[(j * 16 + l16) * 64 + 32 + quad * 8];
      const int k = k0 + j * 16 + l16;
#pragma unroll
      for (int i = 0; i < 2; ++i) {
        f32x4 sc = (f32x4){0.f, 0.f, 0.f, 0.f};
        sc = mfma16(qf[i][0], kf0, sc);
        sc = mfma16(qf[i][1], kf1, sc);
        const int qq = q0 + wv * 32 + i * 16 + quad * 4;
#pragma unroll
        for (int r = 0; r < 4; ++r) {
          float sv = sc[r] * SCL;
          if (edge && ((k > qq + r) || (k >= len))) sv = -1e30f;
          lsum[i][r] += __builtin_amdgcn_exp2f(sv);
        }
      }
    }
  }

  float linv[2][4];
#pragma unroll
  for (int i = 0; i < 2; ++i)
#pragma unroll
    for (int r = 0; r < 4; ++r) {
      float l = lsum[i][r];
      l += __shfl_xor(l, 1);
      l += __shfl_xor(l, 2);
      l += __shfl_xor(l, 4);
      l += __shfl_xor(l, 8);
      linv[i][r] = 1.0f / l;
    }

  // ---- pass 2 ----
  f32x4 oacc[2][4];
#pragma unroll
  for (int i = 0; i < 2; ++i)
#pragma unroll
    for (int jv = 0; jv < 4; ++jv) oacc[i][jv] = (f32x4){0.f, 0.f, 0.f, 0.f};

  const size_t abase = (size_t)(b * HH + h) * SS * SS;

  for (int kt = 0; kt < NKT; ++kt) {
    const int k0 = kt * 128;
    __syncthreads();
#pragma unroll
    for (int it = 0; it < 4; ++it) {
      const int c = it * 256 + tid;
      async16(Kb + (size_t)(b * SS + k0 + (c >> 3)) * DD + h * 64 + (c & 7) * 8,
              &sK[(it * 256 + wv * 64) * 8]);
      async16(Vt + ((size_t)((b * HH + h) * 64 + (c >> 4))) * SS + k0 + (c & 15) * 8,
              &sQV[(it * 256 + wv * 64) * 8]);
    }
    __syncthreads();
    const bool edge = (kt == qt) || (k0 + 128 > len);
#pragma unroll
    for (int j = 0; j < 8; ++j) {
      const bf16x8 kf0 = *(const bf16x8*)&sK[(j * 16 + l16) * 64 + quad * 8];
      const bf16x8 kf1 = *(const bf16x8*)&sK[(j * 16 + l16) * 64 + 32 + quad * 8];
      const int k = k0 + j * 16 + l16;
#pragma unroll
      for (int i = 0; i < 2; ++i) {
        f32x4 sc = (f32x4){0.f, 0.f, 0.f, 0.f};
        sc = mfma16(qf[i][0], kf0, sc);
        sc = mfma16(qf[i][1], kf1, sc);
        const int qq = q0 + wv * 32 + i * 16 + quad * 4;
        const int prow = wv * 4096 + (i * 16 + quad * 4) * 128 + j * 16 + l16;
#pragma unroll
        for (int r = 0; r < 4; ++r) {
          float sv = sc[r] * SCL;
          if (edge && ((k > qq + r) || (k >= len))) sv = -1e30f;
          const float p = __builtin_amdgcn_exp2f(sv) * linv[i][r];
          sP[prow + r * 128] = f2bf(p);
        }
      }
    }
    // vectorized attn tile store: wave's 32x128 sP -> attn_out fp32 (float4)
    {
      const int r2 = lane >> 5, c32 = lane & 31;
      const size_t rowbase = abase + (size_t)(q0 + wv * 32) * SS + k0;
#pragma unroll
      for (int rr = 0; rr < 32; rr += 2) {
        const int row = rr + r2;
        ushort4 u = *(const ushort4*)&sP[wv * 4096 + row * 128 + c32 * 4];
        float4 f;
        f.x = bf2f(u.x); f.y = bf2f(u.y); f.z = bf2f(u.z); f.w = bf2f(u.w);
        *(float4*)&attn_out[rowbase + (size_t)row * SS + c32 * 4] = f;
      }
    }
    // PV: O += P (32x128) * V (128x64), per wave
#pragma unroll
    for (int kk = 0; kk < 4; ++kk) {
      bf16x8 vf[4];
#pragma unroll
      for (int jv = 0; jv < 4; ++jv)
        vf[jv] = *(const bf16x8*)&sQV[(jv * 16 + l16) * 128 + kk * 32 + quad * 8];
#pragma unroll
      for (int i = 0; i < 2; ++i) {
        const bf16x8 pf =
            *(const bf16x8*)&sP[wv * 4096 + (i * 16 + l16) * 128 + kk * 32 + quad * 8];
#pragma unroll
        for (int jv = 0; jv < 4; ++jv) oacc[i][jv] = mfma16(pf, vf[jv], oacc[i][jv]);
      }
    }
  }

  // zero-fill fully-masked column range [NKT*128, S)
  const int Z = SS - NKT * 128;
  if (Z > 0) {
    const int rr0 = tid >> 3;
    const int cf = (tid & 7) * 4;
    for (int rr = rr0; rr < 128; rr += 32) {
      float* dst = attn_out + abase + (size_t)(q0 + rr) * SS + NKT * 128 + cf;
      for (int c8 = 0; c8 < (Z >> 5); ++c8)
        *(float4*)(dst + c8 * 32) = make_float4(0.f, 0.f, 0.f, 0.f);
    }
  }

  // epilogue: stage O in LDS (fp32, reuse sP region), then seq = x + O via float4
  {
    float* sPf = (float*)&sP[wv * 4096];  // 32 x 64 fp32 = 8 KB per wave
#pragma unroll
    for (int i = 0; i < 2; ++i)
#pragma unroll
      for (int jv = 0; jv < 4; ++jv)
#pragma unroll
        for (int r = 0; r < 4; ++r)
          sPf[(i * 16 + quad * 4 + r) * 64 + jv * 16 + l16] = oacc[i][jv][r];
    const int rr = lane >> 4, c4 = (lane & 15) * 4;
#pragma unroll
    for (int it = 0; it < 8; ++it) {
      const int lrow = it * 4 + rr;
      const size_t idx = (size_t)(b * SS + q0 + wv * 32 + lrow) * DD + h * 64 + c4;
      float4 o = *(const float4*)&sPf[lrow * 64 + c4];
      float4 x = *(const float4*)&X[idx];
      o.x += x.x; o.y += x.y; o.z += x.z; o.w += x.w;
      *(float4*)&seq_out[idx] = o;
    }
  }
}

extern "C" void kernel_launch(void* const* d_in, const int* in_sizes, int n_in,
                              void* d_out, int out_size, void* d_ws, size_t ws_size,
                              hipStream_t stream) {
  (void)in_sizes; (void)n_in; (void)out_size; (void)ws_size;
  const float* X     = (const float*)d_in[0];
  const int*   lens  = (const int*)d_in[3];
  const float* gamma = (const float*)d_in[4];
  const float* beta  = (const float*)d_in[5];
  const float* Wq    = (const float*)d_in[6];
  const float* bq    = (const float*)d_in[7];
  const float* Wk    = (const float*)d_in[8];
  const float* bk    = (const float*)d_in[9];
  const float* Wv    = (const float*)d_in[10];
  const float* bv    = (const float*)d_in[11];

  // workspace layout (38 MB total)
  char* ws = (char*)d_ws;
  unsigned short* Xn  = (unsigned short*)(ws);                      // 8 MB
  unsigned short* Qb  = (unsigned short*)(ws + ((size_t)8  << 20)); // 8 MB
  unsigned short* Kb  = (unsigned short*)(ws + ((size_t)16 << 20)); // 8 MB
  unsigned short* Vt  = (unsigned short*)(ws + ((size_t)24 << 20)); // 8 MB  (B*H*64, S)
  unsigned short* Wtq = (unsigned short*)(ws + ((size_t)32 << 20)); // 2 MB
  unsigned short* Wtk = (unsigned short*)(ws + ((size_t)34 << 20)); // 2 MB
  unsigned short* Wtv = (unsigned short*)(ws + ((size_t)36 << 20)); // 2 MB

  float* seq_out  = (float*)d_out;                         // (B,S,1024)
  float* attn_out = seq_out + (size_t)BB * SS * DD;        // (B,H,S,S)

  wtrans_kernel<<<dim3(16, 16, 3), 256, 0, stream>>>(Wq, Wk, Wv, Wtq, Wtk, Wtv);
  ln_kernel<<<dim3(BB * SS), 256, 0, stream>>>(X, gamma, beta, Xn);
  gemm_qkv_kernel<<<dim3(32, 8, 3), 256, 0, stream>>>(Xn, Wtq, Wtk, Wtv, bq, bk, bv, Qb, Kb, Vt);
  attn_kernel<<<dim3(8, HH, BB), 256, 0, stream>>>(Qb, Kb, Vt, X, lens, seq_out, attn_out);
}

// Round 4
// 417.302 us; speedup vs baseline: 1.0551x; 1.0462x over previous
//
#include <hip/hip_runtime.h>
#include <stdint.h>

#define BB 4
#define SS 1024
#define DD 1024
#define HH 16

typedef __attribute__((ext_vector_type(8))) __bf16 bf16x8;
typedef __attribute__((ext_vector_type(4))) float f32x4;

__device__ __forceinline__ unsigned short f2bf(float f) {
  union { float ff; uint32_t u; } a; a.ff = f;
  uint32_t r = a.u + 0x7fffu + ((a.u >> 16) & 1u);
  return (unsigned short)(r >> 16);
}

__device__ __forceinline__ float bf2f(unsigned short u) {
  union { uint32_t uu; float ff; } a; a.uu = ((uint32_t)u) << 16;
  return a.ff;
}

__device__ __forceinline__ f32x4 mfma16(bf16x8 a, bf16x8 b, f32x4 c) {
  return __builtin_amdgcn_mfma_f32_16x16x32_bf16(a, b, c, 0, 0, 0);
}

// global -> LDS direct copy, 16B per lane; LDS dest is wave-uniform base + lane*16
__device__ __forceinline__ void async16(const unsigned short* g, unsigned short* l) {
  __builtin_amdgcn_global_load_lds(
      (__attribute__((address_space(1))) void*)(g),
      (__attribute__((address_space(3))) void*)(l), 16u, 0, 0u);
}

// nontemporal 16B store — must use clang ext_vector_type, not HIP float4 class
__device__ __forceinline__ void nt_store4(float* p, f32x4 v) {
  __builtin_nontemporal_store(v, (f32x4*)p);
}

// ---------- W (K x N fp32) -> Wt (N x K bf16), z selects which of Q/K/V ----------
__global__ __launch_bounds__(256) void wtrans_kernel(const float* __restrict__ Wq,
                                                     const float* __restrict__ Wk,
                                                     const float* __restrict__ Wv,
                                                     unsigned short* __restrict__ Wtq,
                                                     unsigned short* __restrict__ Wtk,
                                                     unsigned short* __restrict__ Wtv) {
  __shared__ unsigned short t[64][65];
  const int z = blockIdx.z;
  const float* W = (z == 0) ? Wq : (z == 1) ? Wk : Wv;
  unsigned short* Wt = (z == 0) ? Wtq : (z == 1) ? Wtk : Wtv;
  const int k0 = blockIdx.x * 64, n0 = blockIdx.y * 64;
  const int c = threadIdx.x & 63, r0 = threadIdx.x >> 6;
#pragma unroll
  for (int i = 0; i < 16; ++i) {
    int r = i * 4 + r0;
    t[r][c] = f2bf(W[(size_t)(k0 + r) * DD + n0 + c]);
  }
  __syncthreads();
#pragma unroll
  for (int i = 0; i < 16; ++i) {
    int n = i * 4 + r0;
    Wt[(size_t)(n0 + n) * DD + k0 + c] = t[c][n];
  }
}

// ---------- LayerNorm (fp32 math) -> bf16 ----------
__global__ __launch_bounds__(256) void ln_kernel(const float* __restrict__ X,
                                                 const float* __restrict__ gamma,
                                                 const float* __restrict__ beta,
                                                 unsigned short* __restrict__ Xn) {
  const int row = blockIdx.x;
  const int tid = threadIdx.x;
  const float* xr = X + (size_t)row * DD;
  float4 v = ((const float4*)xr)[tid];
  float s = v.x + v.y + v.z + v.w;
  float s2 = v.x * v.x + v.y * v.y + v.z * v.z + v.w * v.w;
#pragma unroll
  for (int off = 1; off < 64; off <<= 1) {
    s += __shfl_xor(s, off);
    s2 += __shfl_xor(s2, off);
  }
  __shared__ float red[8];
  const int wv = tid >> 6, lane = tid & 63;
  if (lane == 0) { red[wv] = s; red[4 + wv] = s2; }
  __syncthreads();
  s = red[0] + red[1] + red[2] + red[3];
  s2 = red[4] + red[5] + red[6] + red[7];
  const float mu = s * (1.0f / DD);
  const float rs = rsqrtf(s2 * (1.0f / DD) - mu * mu + 1e-5f);
  float4 g = ((const float4*)gamma)[tid];
  float4 bt = ((const float4*)beta)[tid];
  ushort4 o;
  o.x = f2bf((v.x - mu) * rs * g.x + bt.x);
  o.y = f2bf((v.y - mu) * rs * g.y + bt.y);
  o.z = f2bf((v.z - mu) * rs * g.z + bt.z);
  o.w = f2bf((v.w - mu) * rs * g.w + bt.w);
  ((ushort4*)(Xn + (size_t)row * DD))[tid] = o;
}

// ---------- QKV GEMM: C = Xn (M x K) * Wt^T (Wt is N x K), 128x128 tile ----------
// z==0 -> Qb, z==1 -> Kb (M x N bf16, LDS-staged vectorized store)
// z==2 -> Vt transposed (B*H*64, S) bf16 via transposed LDS staging (256B rows)
__global__ __launch_bounds__(256) void gemm_qkv_kernel(
    const unsigned short* __restrict__ Xn,
    const unsigned short* __restrict__ Wtq, const unsigned short* __restrict__ Wtk,
    const unsigned short* __restrict__ Wtv,
    const float* __restrict__ bq, const float* __restrict__ bk, const float* __restrict__ bv,
    unsigned short* __restrict__ Qb, unsigned short* __restrict__ Kb,
    unsigned short* __restrict__ Vt) {
  // union: [sA 128x32 | sB 128x32] during K-loop, sC 128x136 in epilogue
  __shared__ __align__(16) unsigned short smem[128 * 136];
  unsigned short* sA = smem;
  unsigned short* sB = smem + 128 * 32;
  const int z = blockIdx.z;
  const unsigned short* Wt = (z == 0) ? Wtq : (z == 1) ? Wtk : Wtv;
  const float* bias = (z == 0) ? bq : (z == 1) ? bk : bv;
  const int tid = threadIdx.x;
  const int lane = tid & 63, wv = tid >> 6;
  const int quad = lane >> 4, l16 = lane & 15;
  const int m0 = blockIdx.x * 128, n0 = blockIdx.y * 128;
  const int wm = (wv & 1) * 64, wn = (wv >> 1) * 64;

  f32x4 acc[4][4];
#pragma unroll
  for (int i = 0; i < 4; ++i)
#pragma unroll
    for (int j = 0; j < 4; ++j) acc[i][j] = (f32x4){0.f, 0.f, 0.f, 0.f};

  for (int kt = 0; kt < DD; kt += 32) {
    __syncthreads();
#pragma unroll
    for (int it = 0; it < 2; ++it) {
      const int c = it * 256 + tid;
      const int row = c >> 2, kc = c & 3;
      async16(Xn + (size_t)(m0 + row) * DD + kt + kc * 8, &sA[(it * 256 + wv * 64) * 8]);
      async16(Wt + (size_t)(n0 + row) * DD + kt + kc * 8, &sB[(it * 256 + wv * 64) * 8]);
    }
    __syncthreads();
    bf16x8 af[4], bfr[4];
#pragma unroll
    for (int i = 0; i < 4; ++i) af[i] = *(const bf16x8*)&sA[(wm + i * 16 + l16) * 32 + quad * 8];
#pragma unroll
    for (int j = 0; j < 4; ++j) bfr[j] = *(const bf16x8*)&sB[(wn + j * 16 + l16) * 32 + quad * 8];
#pragma unroll
    for (int i = 0; i < 4; ++i)
#pragma unroll
      for (int j = 0; j < 4; ++j) acc[i][j] = mfma16(af[i], bfr[j], acc[i][j]);
  }

  __syncthreads();
  if (z < 2) {
    // stage C tile (bf16) in padded LDS, then vectorized 16B stores
    unsigned short* sC = smem;  // 128 x 136
#pragma unroll
    for (int i = 0; i < 4; ++i) {
      const int lr0 = wm + i * 16 + quad * 4;
#pragma unroll
      for (int j = 0; j < 4; ++j) {
        const int lc = wn + j * 16 + l16;
        const float bb = bias[n0 + lc];
#pragma unroll
        for (int r = 0; r < 4; ++r) sC[(lr0 + r) * 136 + lc] = f2bf(acc[i][j][r] + bb);
      }
    }
    __syncthreads();
    unsigned short* Out = (z == 0) ? Qb : Kb;
    const int rr = tid >> 4, c8 = (tid & 15) * 8;
#pragma unroll
    for (int it = 0; it < 8; ++it) {
      const int row = it * 16 + rr;
      *(uint4*)&Out[(size_t)(m0 + row) * DD + n0 + c8] = *(const uint4*)&sC[row * 136 + c8];
    }
  } else {
    // transposed staging: sC[dv-local][s-local], then 256B-contiguous row stores
    unsigned short* sC = smem;  // 128 x 136
#pragma unroll
    for (int i = 0; i < 4; ++i) {
      const int lr0 = wm + i * 16 + quad * 4;   // s-local
#pragma unroll
      for (int j = 0; j < 4; ++j) {
        const int lc = wn + j * 16 + l16;       // dv-local (n)
        const float bb = bias[n0 + lc];
#pragma unroll
        for (int r = 0; r < 4; ++r) sC[lc * 136 + lr0 + r] = f2bf(acc[i][j][r] + bb);
      }
    }
    __syncthreads();
    const int b = m0 >> 10, s0 = m0 & 1023;
    const int rr = tid >> 4, c8 = (tid & 15) * 8;
#pragma unroll
    for (int it = 0; it < 8; ++it) {
      const int row = it * 16 + rr;  // dv-local
      const int n = n0 + row;
      unsigned short* dst =
          &Vt[((size_t)((b * HH + (n >> 6)) * 64 + (n & 63))) * SS + s0 + c8];
      *(uint4*)dst = *(const uint4*)&sC[row * 136 + c8];
    }
  }
}

// ---------- fused attention: per (b,h,q-tile 128) ----------
// XOR bank swizzle: physical_chunk = logical_chunk ^ (row & (nchunks-1)),
// applied on the global-address side of global_load_lds so staging stays coalesced.
__global__ __launch_bounds__(256) void attn_kernel(
    const unsigned short* __restrict__ Qb, const unsigned short* __restrict__ Kb,
    const unsigned short* __restrict__ Vt, const float* __restrict__ X,
    const int* __restrict__ lens, float* __restrict__ seq_out,
    float* __restrict__ attn_out) {
  __shared__ unsigned short sQV[128 * 64];    // Q tile (8-chunk rows) / V^T tile (16-chunk rows)
  __shared__ unsigned short sK[128 * 64];     // K tile (8-chunk rows)
  __shared__ unsigned short sP[4 * 32 * 128]; // per-wave P scratch (16-chunk rows)

  const int tid = threadIdx.x;
  const int lane = tid & 63, wv = tid >> 6;
  const int quad = lane >> 4, l16 = lane & 15;
  const int h = blockIdx.y, b = blockIdx.z;
  const int qt = (b & 2) ? (7 - (int)blockIdx.x) : (int)blockIdx.x;
  const int q0 = qt * 128;
  const int len = lens[b];
  const int KE = min(q0 + 128, len);
  const int NKT = (KE + 127) >> 7;
  const float SCL = 0.1803368801111204f;  // 0.125 * log2(e)
  const int s7 = l16 & 7;                 // row&7 for 64-short rows (row = ..+l16)

  // ---- stage Q (swizzled) ----
#pragma unroll
  for (int it = 0; it < 4; ++it) {
    const int c = it * 256 + tid;
    const int row = c >> 3, ch = (c & 7) ^ (row & 7);
    async16(Qb + (size_t)(b * SS + q0 + row) * DD + h * 64 + ch * 8,
            &sQV[(it * 256 + wv * 64) * 8]);
  }
  __syncthreads();

  bf16x8 qf[2][2];
#pragma unroll
  for (int i = 0; i < 2; ++i)
#pragma unroll
    for (int dd = 0; dd < 2; ++dd)
      qf[i][dd] = *(const bf16x8*)
          &sQV[(wv * 32 + i * 16 + l16) * 64 + ((dd * 4 + quad) ^ s7) * 8];

  float lsum[2][4];
#pragma unroll
  for (int i = 0; i < 2; ++i)
#pragma unroll
    for (int r = 0; r < 4; ++r) lsum[i][r] = 0.f;

  // ---- pass 1: denominators ----
  for (int kt = 0; kt < NKT; ++kt) {
    const int k0 = kt * 128;
    __syncthreads();
#pragma unroll
    for (int it = 0; it < 4; ++it) {
      const int c = it * 256 + tid;
      const int row = c >> 3, ch = (c & 7) ^ (row & 7);
      async16(Kb + (size_t)(b * SS + k0 + row) * DD + h * 64 + ch * 8,
              &sK[(it * 256 + wv * 64) * 8]);
    }
    __syncthreads();
    const bool edge = (kt == qt) || (k0 + 128 > len);
#pragma unroll
    for (int j = 0; j < 8; ++j) {
      const bf16x8 kf0 = *(const bf16x8*)&sK[(j * 16 + l16) * 64 + ((0 + quad) ^ s7) * 8];
      const bf16x8 kf1 = *(const bf16x8*)&sK[(j * 16 + l16) * 64 + ((4 + quad) ^ s7) * 8];
      const int k = k0 + j * 16 + l16;
#pragma unroll
      for (int i = 0; i < 2; ++i) {
        f32x4 sc = (f32x4){0.f, 0.f, 0.f, 0.f};
        sc = mfma16(qf[i][0], kf0, sc);
        sc = mfma16(qf[i][1], kf1, sc);
        const int qq = q0 + wv * 32 + i * 16 + quad * 4;
#pragma unroll
        for (int r = 0; r < 4; ++r) {
          float sv = sc[r] * SCL;
          if (edge && ((k > qq + r) || (k >= len))) sv = -1e30f;
          lsum[i][r] += __builtin_amdgcn_exp2f(sv);
        }
      }
    }
  }

  float linv[2][4];
#pragma unroll
  for (int i = 0; i < 2; ++i)
#pragma unroll
    for (int r = 0; r < 4; ++r) {
      float l = lsum[i][r];
      l += __shfl_xor(l, 1);
      l += __shfl_xor(l, 2);
      l += __shfl_xor(l, 4);
      l += __shfl_xor(l, 8);
      linv[i][r] = 1.0f / l;
    }

  // ---- pass 2 ----
  f32x4 oacc[2][4];
#pragma unroll
  for (int i = 0; i < 2; ++i)
#pragma unroll
    for (int jv = 0; jv < 4; ++jv) oacc[i][jv] = (f32x4){0.f, 0.f, 0.f, 0.f};

  const size_t abase = (size_t)(b * HH + h) * SS * SS;

  for (int kt = 0; kt < NKT; ++kt) {
    const int k0 = kt * 128;
    __syncthreads();
#pragma unroll
    for (int it = 0; it < 4; ++it) {
      const int c = it * 256 + tid;
      const int krow = c >> 3, kch = (c & 7) ^ (krow & 7);
      async16(Kb + (size_t)(b * SS + k0 + krow) * DD + h * 64 + kch * 8,
              &sK[(it * 256 + wv * 64) * 8]);
      const int vrow = c >> 4, vch = (c & 15) ^ (vrow & 15);
      async16(Vt + ((size_t)((b * HH + h) * 64 + vrow)) * SS + k0 + vch * 8,
              &sQV[(it * 256 + wv * 64) * 8]);
    }
    __syncthreads();
    const bool edge = (kt == qt) || (k0 + 128 > len);
#pragma unroll
    for (int j = 0; j < 8; ++j) {
      const bf16x8 kf0 = *(const bf16x8*)&sK[(j * 16 + l16) * 64 + ((0 + quad) ^ s7) * 8];
      const bf16x8 kf1 = *(const bf16x8*)&sK[(j * 16 + l16) * 64 + ((4 + quad) ^ s7) * 8];
      const int k = k0 + j * 16 + l16;
#pragma unroll
      for (int i = 0; i < 2; ++i) {
        f32x4 sc = (f32x4){0.f, 0.f, 0.f, 0.f};
        sc = mfma16(qf[i][0], kf0, sc);
        sc = mfma16(qf[i][1], kf1, sc);
        const int qq = q0 + wv * 32 + i * 16 + quad * 4;
#pragma unroll
        for (int r = 0; r < 4; ++r) {
          float sv = sc[r] * SCL;
          if (edge && ((k > qq + r) || (k >= len))) sv = -1e30f;
          const float p = __builtin_amdgcn_exp2f(sv) * linv[i][r];
          const int prow = i * 16 + quad * 4 + r;           // 0..31
          const int pch = (2 * j + (l16 >> 3)) ^ (prow & 15);
          sP[wv * 4096 + prow * 128 + pch * 8 + (l16 & 7)] = f2bf(p);
        }
      }
    }
    // vectorized attn tile store (nt): wave's 32x128 sP -> attn_out fp32
    {
      const int r2 = lane >> 5, c32 = lane & 31;
#pragma unroll
      for (int rr = 0; rr < 32; rr += 2) {
        const int row = rr + r2;
        const int ch = (c32 >> 1) ^ (row & 15);
        ushort4 u = *(const ushort4*)&sP[wv * 4096 + row * 128 + ch * 8 + (c32 & 1) * 4];
        f32x4 f;
        f[0] = bf2f(u.x); f[1] = bf2f(u.y); f[2] = bf2f(u.z); f[3] = bf2f(u.w);
        nt_store4(&attn_out[abase + (size_t)(q0 + wv * 32 + row) * SS + k0 + c32 * 4], f);
      }
    }
    // PV: O += P (32x128) * V (128x64), per wave
#pragma unroll
    for (int kk = 0; kk < 4; ++kk) {
      bf16x8 vf[4];
#pragma unroll
      for (int jv = 0; jv < 4; ++jv)
        vf[jv] = *(const bf16x8*)
            &sQV[(jv * 16 + l16) * 128 + (((kk * 4 + quad) ^ l16) & 15) * 8];
#pragma unroll
      for (int i = 0; i < 2; ++i) {
        const bf16x8 pf = *(const bf16x8*)
            &sP[wv * 4096 + (i * 16 + l16) * 128 + ((kk * 4 + quad) ^ l16) * 8];
#pragma unroll
        for (int jv = 0; jv < 4; ++jv) oacc[i][jv] = mfma16(pf, vf[jv], oacc[i][jv]);
      }
    }
  }

  // zero-fill fully-masked column range [NKT*128, S)
  const int Z = SS - NKT * 128;
  if (Z > 0) {
    const int rr0 = tid >> 3;
    const int cf = (tid & 7) * 4;
    const f32x4 zz = (f32x4){0.f, 0.f, 0.f, 0.f};
    for (int rr = rr0; rr < 128; rr += 32) {
      float* dst = attn_out + abase + (size_t)(q0 + rr) * SS + NKT * 128 + cf;
      for (int c8 = 0; c8 < (Z >> 5); ++c8) nt_store4(dst + c8 * 32, zz);
    }
  }

  // epilogue: stage O in LDS (fp32, reuse sP region), then seq = x + O via float4
  __syncthreads();
  {
    float* sPf = (float*)&sP[wv * 4096];  // 32 x 64 fp32 = 8 KB per wave
#pragma unroll
    for (int i = 0; i < 2; ++i)
#pragma unroll
      for (int jv = 0; jv < 4; ++jv)
#pragma unroll
        for (int r = 0; r < 4; ++r)
          sPf[(i * 16 + quad * 4 + r) * 64 + jv * 16 + l16] = oacc[i][jv][r];
    const int rr = lane >> 4, c4 = (lane & 15) * 4;
#pragma unroll
    for (int it = 0; it < 8; ++it) {
      const int lrow = it * 4 + rr;
      const size_t idx = (size_t)(b * SS + q0 + wv * 32 + lrow) * DD + h * 64 + c4;
      float4 o = *(const float4*)&sPf[lrow * 64 + c4];
      float4 x = *(const float4*)&X[idx];
      o.x += x.x; o.y += x.y; o.z += x.z; o.w += x.w;
      *(float4*)&seq_out[idx] = o;
    }
  }
}

extern "C" void kernel_launch(void* const* d_in, const int* in_sizes, int n_in,
                              void* d_out, int out_size, void* d_ws, size_t ws_size,
                              hipStream_t stream) {
  (void)in_sizes; (void)n_in; (void)out_size; (void)ws_size;
  const float* X     = (const float*)d_in[0];
  const int*   lens  = (const int*)d_in[3];
  const float* gamma = (const float*)d_in[4];
  const float* beta  = (const float*)d_in[5];
  const float* Wq    = (const float*)d_in[6];
  const float* bq    = (const float*)d_in[7];
  const float* Wk    = (const float*)d_in[8];
  const float* bk    = (const float*)d_in[9];
  const float* Wv    = (const float*)d_in[10];
  const float* bv    = (const float*)d_in[11];

  // workspace layout (38 MB total)
  char* ws = (char*)d_ws;
  unsigned short* Xn  = (unsigned short*)(ws);                      // 8 MB
  unsigned short* Qb  = (unsigned short*)(ws + ((size_t)8  << 20)); // 8 MB
  unsigned short* Kb  = (unsigned short*)(ws + ((size_t)16 << 20)); // 8 MB
  unsigned short* Vt  = (unsigned short*)(ws + ((size_t)24 << 20)); // 8 MB  (B*H*64, S)
  unsigned short* Wtq = (unsigned short*)(ws + ((size_t)32 << 20)); // 2 MB
  unsigned short* Wtk = (unsigned short*)(ws + ((size_t)34 << 20)); // 2 MB
  unsigned short* Wtv = (unsigned short*)(ws + ((size_t)36 << 20)); // 2 MB

  float* seq_out  = (float*)d_out;                         // (B,S,1024)
  float* attn_out = seq_out + (size_t)BB * SS * DD;        // (B,H,S,S)

  wtrans_kernel<<<dim3(16, 16, 3), 256, 0, stream>>>(Wq, Wk, Wv, Wtq, Wtk, Wtv);
  ln_kernel<<<dim3(BB * SS), 256, 0, stream>>>(X, gamma, beta, Xn);
  gemm_qkv_kernel<<<dim3(32, 8, 3), 256, 0, stream>>>(Xn, Wtq, Wtk, Wtv, bq, bk, bv, Qb, Kb, Vt);
  attn_kernel<<<dim3(8, HH, BB), 256, 0, stream>>>(Qb, Kb, Vt, X, lens, seq_out, attn_out);
}